// Round 2
// baseline (1026.446 us; speedup 1.0000x reference)
//
#include <hip/hip_runtime.h>
#include <hip/hip_bf16.h>

#define NN 50000
#define NE 800000
#define DD 64
#define HH 128
#define KK 192   // 3*DD

typedef __bf16 bf16;
typedef __attribute__((ext_vector_type(8))) __bf16 bf16x8;
typedef __attribute__((ext_vector_type(4))) __bf16 bf16x4;
typedef __attribute__((ext_vector_type(4))) float f32x4;

// jax.nn.gelu(approximate=True) = x * sigmoid(1.702...*x) exact tanh form:
__device__ __forceinline__ float gelu_tanh(float x) {
    float v = 1.5957691216057308f * x * (1.0f + 0.044715f * x * x);
    return x / (1.0f + __expf(-v));
}

// ---------------------------------------------------------------------------
// CSR build: count -> scan (single block) -> fill
// ---------------------------------------------------------------------------
extern "C" __global__ void count_kernel(const int* __restrict__ src,
                                        const int* __restrict__ dst,
                                        int* __restrict__ cnt_s, int* __restrict__ cnt_d)
{
    int i = blockIdx.x * blockDim.x + threadIdx.x;
    const int stride = gridDim.x * blockDim.x;
    for (; i < NE; i += stride) {
        atomicAdd(&cnt_s[src[i]], 1);
        atomicAdd(&cnt_d[dst[i]], 1);
    }
}

extern "C" __global__ void __launch_bounds__(1024)
scan_kernel(const int* __restrict__ cnt_s, const int* __restrict__ cnt_d,
            int* __restrict__ ptr_s, int* __restrict__ ptr_d,
            int* __restrict__ cur_s, int* __restrict__ cur_d)
{
    __shared__ int wt_s[16], wt_d[16];
    __shared__ int carry[2];
    const int t = threadIdx.x, lane = t & 63, wave = t >> 6;
    if (t == 0) { carry[0] = 0; carry[1] = 0; }
    __syncthreads();
    for (int base = 0; base < NN; base += 1024) {
        const int i = base + t;
        const int cs = (i < NN) ? cnt_s[i] : 0;
        const int cd = (i < NN) ? cnt_d[i] : 0;
        int vs = cs, vd = cd;
#pragma unroll
        for (int off = 1; off < 64; off <<= 1) {
            int us = __shfl_up(vs, off, 64);
            int ud = __shfl_up(vd, off, 64);
            if (lane >= off) { vs += us; vd += ud; }
        }
        if (lane == 63) { wt_s[wave] = vs; wt_d[wave] = vd; }
        __syncthreads();
        if (wave == 0) {
            int ws_ = (lane < 16) ? wt_s[lane] : 0;
            int wd_ = (lane < 16) ? wt_d[lane] : 0;
#pragma unroll
            for (int off = 1; off < 16; off <<= 1) {
                int us = __shfl_up(ws_, off, 64);
                int ud = __shfl_up(wd_, off, 64);
                if (lane >= off) { ws_ += us; wd_ += ud; }
            }
            if (lane < 16) { wt_s[lane] = ws_; wt_d[lane] = wd_; }
        }
        __syncthreads();
        const int pre_s = ((wave > 0) ? wt_s[wave - 1] : 0) + carry[0];
        const int pre_d = ((wave > 0) ? wt_d[wave - 1] : 0) + carry[1];
        const int tot_s = wt_s[15], tot_d = wt_d[15];
        if (i < NN) {
            const int es = vs - cs + pre_s;
            const int ed = vd - cd + pre_d;
            ptr_s[i] = es; cur_s[i] = es;
            ptr_d[i] = ed; cur_d[i] = ed;
        }
        __syncthreads();
        if (t == 0) { carry[0] += tot_s; carry[1] += tot_d; }
        __syncthreads();
    }
}

extern "C" __global__ void fill_kernel(const int* __restrict__ src,
                                       const int* __restrict__ dst,
                                       int* __restrict__ cur_s, int* __restrict__ cur_d,
                                       int* __restrict__ eids, int* __restrict__ eidd)
{
    int i = blockIdx.x * blockDim.x + threadIdx.x;
    const int stride = gridDim.x * blockDim.x;
    for (; i < NE; i += stride) {
        const int ps = atomicAdd(&cur_s[src[i]], 1);
        eids[ps] = i;
        const int pd = atomicAdd(&cur_d[dst[i]], 1);
        eidd[pd] = i;
    }
}

// ---------------------------------------------------------------------------
// Edge kernel: 64-edge tiles, 4 waves, 16 rows/wave. No atomics.
// LDS: W1T (B-layout) + XH union buffer (Xs staging / per-wave Hs).
// W2 fragments live in VGPRs. 76.8 KB LDS -> 2 blocks/CU.
// MFMA 16x16x32 bf16 layouts (verified m89/m91/m120):
//   A[m][k]: m=lane&15, k=(lane>>4)*8+j ; B[k][n]: n=lane&15, k=(lane>>4)*8+j
//   C/D: col=lane&15, row=(lane>>4)*4+reg
// ---------------------------------------------------------------------------
extern "C" __global__ void __launch_bounds__(256, 2)
edge_mlp_kernel(const float* __restrict__ ndata, const float* __restrict__ edata,
                const int* __restrict__ src, const int* __restrict__ dst,
                const float* __restrict__ W1, const float* __restrict__ b1,
                const float* __restrict__ W2, const float* __restrict__ b2,
                const float* __restrict__ gam, const float* __restrict__ bet,
                float* __restrict__ eout)
{
    __shared__ __align__(16) bf16 W1T[HH][200];   // [n][k], 51200 B
    __shared__ __align__(16) bf16 XH[64][200];    // union: W2T stage / Xs / Hs, 25600 B

    const int tid = threadIdx.x;
    const int wave = tid >> 6;
    const int lane = tid & 63;
    const int l15  = lane & 15;
    const int quad = lane >> 4;
    const int r_st = tid >> 2;   // staging row 0..63 (wave-private: rows 16w..16w+15)
    const int l_st = tid & 3;

    // stage W1T; stage W2T temporarily into XH, pull fragments to registers
    for (int i = tid; i < KK * HH; i += 256) W1T[i % HH][i / HH] = (bf16)W1[i];
    for (int i = tid; i < HH * DD; i += 256) XH[i & 63][i >> 6] = (bf16)W2[i];
    __syncthreads();
    bf16x8 w2f[4][4];
#pragma unroll
    for (int nt = 0; nt < 4; ++nt)
#pragma unroll
        for (int s = 0; s < 4; ++s)
            w2f[nt][s] = *(const bf16x8*)&XH[nt * 16 + l15][s * 32 + quad * 8];
    __syncthreads();

    float b1v[8], b2v[4], gv[4], bv[4];
#pragma unroll
    for (int nt = 0; nt < 8; ++nt) b1v[nt] = b1[nt * 16 + l15];
#pragma unroll
    for (int nt = 0; nt < 4; ++nt) {
        b2v[nt] = b2[nt * 16 + l15];
        gv[nt]  = gam[nt * 16 + l15];
        bv[nt]  = bet[nt * 16 + l15];
    }

    for (int tile = blockIdx.x; tile < NE / 64; tile += gridDim.x) {
        const int e0 = tile * 64;
        // gather X = [ndata[src] | ndata[dst] | edata] -> bf16 LDS (wave-private rows)
        {
            const int e = e0 + r_st;
            const float* base0 = ndata + (size_t)src[e] * DD;
            const float* base1 = ndata + (size_t)dst[e] * DD;
            const float* base2 = edata + (size_t)e * DD;
#pragma unroll
            for (int seg = 0; seg < 3; ++seg) {
                const float* bp = (seg == 0) ? base0 : ((seg == 1) ? base1 : base2);
#pragma unroll
                for (int jj = 0; jj < 4; ++jj) {
                    const int kk = l_st * 16 + jj * 4;
                    const float4 v = *(const float4*)(bp + kk);
                    bf16x4 w = { (bf16)v.x, (bf16)v.y, (bf16)v.z, (bf16)v.w };
                    *(bf16x4*)&XH[r_st][seg * 64 + kk] = w;
                }
            }
        }
        // GEMM1 (A-frags loaded to regs first; Hs then overwrites own-wave rows)
        const int arow = wave * 16 + l15;
        bf16x8 af[6];
#pragma unroll
        for (int s = 0; s < 6; ++s)
            af[s] = *(const bf16x8*)&XH[arow][s * 32 + quad * 8];
        bf16 hfrag[8][4];
#pragma unroll
        for (int nt = 0; nt < 8; ++nt) {
            f32x4 acc = {0.f, 0.f, 0.f, 0.f};
#pragma unroll
            for (int s = 0; s < 6; ++s) {
                bf16x8 bfr = *(const bf16x8*)&W1T[nt * 16 + l15][s * 32 + quad * 8];
                acc = __builtin_amdgcn_mfma_f32_16x16x32_bf16(af[s], bfr, acc, 0, 0, 0);
            }
#pragma unroll
            for (int r = 0; r < 4; ++r)
                XH[wave * 16 + quad * 4 + r][nt * 16 + l15] = (bf16)gelu_tanh(acc[r] + b1v[nt]);
        }
        // GEMM2 (W2 from registers)
        bf16x8 af2[4];
#pragma unroll
        for (int s = 0; s < 4; ++s)
            af2[s] = *(const bf16x8*)&XH[wave * 16 + l15][s * 32 + quad * 8];
        float yv[4][4];
        float ps[4] = {0.f, 0.f, 0.f, 0.f}, pq[4] = {0.f, 0.f, 0.f, 0.f};
#pragma unroll
        for (int nt = 0; nt < 4; ++nt) {
            f32x4 acc = {0.f, 0.f, 0.f, 0.f};
#pragma unroll
            for (int s = 0; s < 4; ++s)
                acc = __builtin_amdgcn_mfma_f32_16x16x32_bf16(af2[s], w2f[nt][s], acc, 0, 0, 0);
#pragma unroll
            for (int r = 0; r < 4; ++r) {
                const float y = acc[r] + b2v[nt];
                yv[nt][r] = y;
                ps[r] += y;
                pq[r] += y * y;
            }
        }
        // LayerNorm across the 16 lanes of each quad
#pragma unroll
        for (int m = 1; m < 16; m <<= 1) {
#pragma unroll
            for (int r = 0; r < 4; ++r) {
                ps[r] += __shfl_xor(ps[r], m, 64);
                pq[r] += __shfl_xor(pq[r], m, 64);
            }
        }
#pragma unroll
        for (int r = 0; r < 4; ++r) {
            const int row = e0 + wave * 16 + quad * 4 + r;
            const float mu  = ps[r] * (1.0f / 64.0f);
            const float var = pq[r] * (1.0f / 64.0f) - mu * mu;
            const float rs  = rsqrtf(var + 1e-5f);
#pragma unroll
            for (int nt = 0; nt < 4; ++nt) {
                const int col = nt * 16 + l15;
                eout[(size_t)row * DD + col] = (yv[nt][r] - mu) * rs * gv[nt] + bv[nt];
            }
        }
    }
}

// ---------------------------------------------------------------------------
// Node kernel: 64 nodes per block; eu/ev computed by CSR gather over eout.
// ---------------------------------------------------------------------------
extern "C" __global__ void __launch_bounds__(256, 2)
node_mlp_kernel(const float* __restrict__ ndata, const float* __restrict__ eout,
                const int* __restrict__ cnt_s, const int* __restrict__ cnt_d,
                const int* __restrict__ ptr_s, const int* __restrict__ ptr_d,
                const int* __restrict__ eids, const int* __restrict__ eidd,
                const float* __restrict__ W1, const float* __restrict__ b1,
                const float* __restrict__ W2, const float* __restrict__ b2,
                const float* __restrict__ gam, const float* __restrict__ bet,
                float* __restrict__ nout)
{
    __shared__ __align__(16) bf16 W1T[HH][200];
    __shared__ __align__(16) bf16 XH[64][200];

    const int tid = threadIdx.x;
    const int wave = tid >> 6;
    const int lane = tid & 63;
    const int l15  = lane & 15;
    const int quad = lane >> 4;
    const int r_st = tid >> 2;
    const int l_st = tid & 3;

    for (int i = tid; i < KK * HH; i += 256) W1T[i % HH][i / HH] = (bf16)W1[i];
    for (int i = tid; i < HH * DD; i += 256) XH[i & 63][i >> 6] = (bf16)W2[i];
    __syncthreads();
    bf16x8 w2f[4][4];
#pragma unroll
    for (int nt = 0; nt < 4; ++nt)
#pragma unroll
        for (int s = 0; s < 4; ++s)
            w2f[nt][s] = *(const bf16x8*)&XH[nt * 16 + l15][s * 32 + quad * 8];
    __syncthreads();

    float b1v[8], b2v[4], gv[4], bv[4];
#pragma unroll
    for (int nt = 0; nt < 8; ++nt) b1v[nt] = b1[nt * 16 + l15];
#pragma unroll
    for (int nt = 0; nt < 4; ++nt) {
        b2v[nt] = b2[nt * 16 + l15];
        gv[nt]  = gam[nt * 16 + l15];
        bv[nt]  = bet[nt * 16 + l15];
    }

    const int n0 = blockIdx.x * 64;
    const int n  = n0 + r_st;  // this thread's node; cols l_st*16 .. +15

    // gather x_n = [mean_src(eout) | mean_dst(eout) | ndata] -> bf16 XH rows
    if (n < NN) {
#pragma unroll
        for (int seg = 0; seg < 2; ++seg) {
            const int  deg = (seg == 0) ? cnt_s[n] : cnt_d[n];
            const int  p0  = (seg == 0) ? ptr_s[n] : ptr_d[n];
            const int* el  = (seg == 0) ? eids : eidd;
            f32x4 a0 = {0.f,0.f,0.f,0.f}, a1 = a0, a2 = a0, a3 = a0;
            int e = (deg > 0) ? el[p0] : 0;
            for (int j = 0; j < deg; ++j) {
                const int en = (j + 1 < deg) ? el[p0 + j + 1] : 0;
                const f32x4* rp = (const f32x4*)(eout + (size_t)e * DD + l_st * 16);
                a0 += rp[0]; a1 += rp[1]; a2 += rp[2]; a3 += rp[3];
                e = en;
            }
            const float sc = 1.0f / fmaxf((float)deg, 1.0f);
            const int c0 = seg * 64 + l_st * 16;
            bf16x4 w0 = { (bf16)(a0[0]*sc), (bf16)(a0[1]*sc), (bf16)(a0[2]*sc), (bf16)(a0[3]*sc) };
            bf16x4 w1 = { (bf16)(a1[0]*sc), (bf16)(a1[1]*sc), (bf16)(a1[2]*sc), (bf16)(a1[3]*sc) };
            bf16x4 w2 = { (bf16)(a2[0]*sc), (bf16)(a2[1]*sc), (bf16)(a2[2]*sc), (bf16)(a2[3]*sc) };
            bf16x4 w3 = { (bf16)(a3[0]*sc), (bf16)(a3[1]*sc), (bf16)(a3[2]*sc), (bf16)(a3[3]*sc) };
            *(bf16x4*)&XH[r_st][c0 + 0]  = w0;
            *(bf16x4*)&XH[r_st][c0 + 4]  = w1;
            *(bf16x4*)&XH[r_st][c0 + 8]  = w2;
            *(bf16x4*)&XH[r_st][c0 + 12] = w3;
        }
        {
            const float* bp = ndata + (size_t)n * DD;
#pragma unroll
            for (int jj = 0; jj < 4; ++jj) {
                const int kk = l_st * 16 + jj * 4;
                const float4 v = *(const float4*)(bp + kk);
                bf16x4 w = { (bf16)v.x, (bf16)v.y, (bf16)v.z, (bf16)v.w };
                *(bf16x4*)&XH[r_st][128 + kk] = w;
            }
        }
    } else {
        bf16x4 z = { (bf16)0.f, (bf16)0.f, (bf16)0.f, (bf16)0.f };
#pragma unroll
        for (int seg = 0; seg < 3; ++seg)
#pragma unroll
            for (int jj = 0; jj < 4; ++jj)
                *(bf16x4*)&XH[r_st][seg * 64 + l_st * 16 + jj * 4] = z;
    }

    // GEMM1
    const int arow = wave * 16 + l15;
    bf16x8 af[6];
#pragma unroll
    for (int s = 0; s < 6; ++s)
        af[s] = *(const bf16x8*)&XH[arow][s * 32 + quad * 8];
#pragma unroll
    for (int nt = 0; nt < 8; ++nt) {
        f32x4 acc = {0.f, 0.f, 0.f, 0.f};
#pragma unroll
        for (int s = 0; s < 6; ++s) {
            bf16x8 bfr = *(const bf16x8*)&W1T[nt * 16 + l15][s * 32 + quad * 8];
            acc = __builtin_amdgcn_mfma_f32_16x16x32_bf16(af[s], bfr, acc, 0, 0, 0);
        }
#pragma unroll
        for (int r = 0; r < 4; ++r)
            XH[wave * 16 + quad * 4 + r][nt * 16 + l15] = (bf16)gelu_tanh(acc[r] + b1v[nt]);
    }
    // GEMM2
    bf16x8 af2[4];
#pragma unroll
    for (int s = 0; s < 4; ++s)
        af2[s] = *(const bf16x8*)&XH[wave * 16 + l15][s * 32 + quad * 8];
    float yv[4][4];
    float ps[4] = {0.f, 0.f, 0.f, 0.f}, pq[4] = {0.f, 0.f, 0.f, 0.f};
#pragma unroll
    for (int nt = 0; nt < 4; ++nt) {
        f32x4 acc = {0.f, 0.f, 0.f, 0.f};
#pragma unroll
        for (int s = 0; s < 4; ++s)
            acc = __builtin_amdgcn_mfma_f32_16x16x32_bf16(af2[s], w2f[nt][s], acc, 0, 0, 0);
#pragma unroll
        for (int r = 0; r < 4; ++r) {
            const float y = acc[r] + b2v[nt];
            yv[nt][r] = y;
            ps[r] += y;
            pq[r] += y * y;
        }
    }
#pragma unroll
    for (int m = 1; m < 16; m <<= 1) {
#pragma unroll
        for (int r = 0; r < 4; ++r) {
            ps[r] += __shfl_xor(ps[r], m, 64);
            pq[r] += __shfl_xor(pq[r], m, 64);
        }
    }
#pragma unroll
    for (int r = 0; r < 4; ++r) {
        const int row = n0 + wave * 16 + quad * 4 + r;
        if (row < NN) {
            const float mu  = ps[r] * (1.0f / 64.0f);
            const float var = pq[r] * (1.0f / 64.0f) - mu * mu;
            const float rs  = rsqrtf(var + 1e-5f);
#pragma unroll
            for (int nt = 0; nt < 4; ++nt) {
                const int col = nt * 16 + l15;
                nout[(size_t)row * DD + col] = (yv[nt][r] - mu) * rs * gv[nt] + bv[nt];
            }
        }
    }
}

extern "C" void kernel_launch(void* const* d_in, const int* in_sizes, int n_in,
                              void* d_out, int out_size, void* d_ws, size_t ws_size,
                              hipStream_t stream)
{
    const float* ndata = (const float*)d_in[0];
    const float* edata = (const float*)d_in[1];
    const int*   src   = (const int*)d_in[2];
    const int*   dst   = (const int*)d_in[3];
    const float* eW1 = (const float*)d_in[4];
    const float* eb1 = (const float*)d_in[5];
    const float* eW2 = (const float*)d_in[6];
    const float* eb2 = (const float*)d_in[7];
    const float* eg  = (const float*)d_in[8];
    const float* ebt = (const float*)d_in[9];
    const float* nW1 = (const float*)d_in[10];
    const float* nb1 = (const float*)d_in[11];
    const float* nW2 = (const float*)d_in[12];
    const float* nb2 = (const float*)d_in[13];
    const float* ng  = (const float*)d_in[14];
    const float* nbt = (const float*)d_in[15];

    float* out  = (float*)d_out;
    float* nout = out;                       // ndata_new [NN*DD]
    float* eout = out + (size_t)NN * DD;     // edata_new [NE*DD]

    int* cnt_s = (int*)d_ws;
    int* cnt_d = cnt_s + NN;
    int* ptr_s = cnt_d + NN;
    int* ptr_d = ptr_s + NN;
    int* cur_s = ptr_d + NN;
    int* cur_d = cur_s + NN;
    int* eids  = cur_d + NN;
    int* eidd  = eids + NE;

    hipMemsetAsync(cnt_s, 0, 2 * NN * sizeof(int), stream);
    hipLaunchKernelGGL(count_kernel, dim3(1024), dim3(256), 0, stream,
                       src, dst, cnt_s, cnt_d);
    hipLaunchKernelGGL(scan_kernel, dim3(1), dim3(1024), 0, stream,
                       cnt_s, cnt_d, ptr_s, ptr_d, cur_s, cur_d);
    hipLaunchKernelGGL(fill_kernel, dim3(1024), dim3(256), 0, stream,
                       src, dst, cur_s, cur_d, eids, eidd);
    hipLaunchKernelGGL(edge_mlp_kernel, dim3(512), dim3(256), 0, stream,
                       ndata, edata, src, dst, eW1, eb1, eW2, eb2, eg, ebt, eout);
    hipLaunchKernelGGL(node_mlp_kernel, dim3((NN + 63) / 64), dim3(256), 0, stream,
                       ndata, eout, cnt_s, cnt_d, ptr_s, ptr_d, eids, eidd,
                       nW1, nb1, nW2, nb2, ng, nbt, nout);
}

// Round 3
// 750.429 us; speedup vs baseline: 1.3678x; 1.3678x over previous
//
#include <hip/hip_runtime.h>
#include <hip/hip_bf16.h>

#define NN 50000
#define NE 800000
#define DD 64
#define HH 128
#define KK 192   // 3*DD
#define LDW 208  // LDS row stride (bf16 elems): 416B, 16B-aligned rows

typedef __bf16 bf16;
typedef __attribute__((ext_vector_type(8))) __bf16 bf16x8;
typedef __attribute__((ext_vector_type(4))) __bf16 bf16x4;
typedef __attribute__((ext_vector_type(4))) float f32x4;

// jax.nn.gelu tanh-approx: x * sigmoid(1.5957691*(x + 0.044715 x^3))
__device__ __forceinline__ float gelu_tanh(float x) {
    float v = 1.5957691216057308f * x * (1.0f + 0.044715f * x * x);
    return x / (1.0f + __expf(-v));
}

// ---------------------------------------------------------------------------
// Edge kernel: 64-edge tiles, 4 waves, 16 rows/wave, software-pipelined gather.
// Aggregation fused via fire-and-forget f32 atomics (no CSR).
// LDS: W1T (B-layout, padded) + XH union (X staging / per-wave Hs). ~80KB ->
// 2 blocks/CU; grid=512 => fully resident persistent blocks.
// MFMA 16x16x32 bf16 layouts (verified m89/m91/m120):
//   A[m][k]: m=lane&15, k=(lane>>4)*8+j ; B[k][n]: n=lane&15, k=(lane>>4)*8+j
//   C/D: col=lane&15, row=(lane>>4)*4+reg
// ---------------------------------------------------------------------------
extern "C" __global__ void __launch_bounds__(256, 2)
edge_mlp_kernel(const float* __restrict__ ndata, const float* __restrict__ edata,
                const int* __restrict__ src, const int* __restrict__ dst,
                const float* __restrict__ W1, const float* __restrict__ b1,
                const float* __restrict__ W2, const float* __restrict__ b2,
                const float* __restrict__ gam, const float* __restrict__ bet,
                float* __restrict__ eout,
                float* __restrict__ eu, float* __restrict__ ev,
                float* __restrict__ cnts, float* __restrict__ cntd)
{
    __shared__ __align__(16) bf16 W1T[HH][LDW];   // [n][k], 53248 B
    __shared__ __align__(16) bf16 XH[64][LDW];    // union: W2T stage / Xs / Hs, 26624 B

    const int tid = threadIdx.x;
    const int wave = tid >> 6;
    const int lane = tid & 63;
    const int l15  = lane & 15;
    const int quad = lane >> 4;
    const int r_st = tid >> 2;   // staging row 0..63 (wave-private: rows 16w..16w+15)
    const int l_st = tid & 3;

    // stage W1T; stage W2T temporarily into XH, pull fragments to registers
    for (int i = tid; i < KK * HH; i += 256) W1T[i & 127][i >> 7] = (bf16)W1[i];
    for (int i = tid; i < HH * DD; i += 256) XH[i & 63][i >> 6] = (bf16)W2[i];
    __syncthreads();
    bf16x8 w2f[4][4];
#pragma unroll
    for (int nt = 0; nt < 4; ++nt)
#pragma unroll
        for (int s = 0; s < 4; ++s)
            w2f[nt][s] = *(const bf16x8*)&XH[nt * 16 + l15][s * 32 + quad * 8];
    __syncthreads();

    float b1v[8], b2v[4], gv[4], bv[4];
#pragma unroll
    for (int nt = 0; nt < 8; ++nt) b1v[nt] = b1[nt * 16 + l15];
#pragma unroll
    for (int nt = 0; nt < 4; ++nt) {
        b2v[nt] = b2[nt * 16 + l15];
        gv[nt]  = gam[nt * 16 + l15];
        bv[nt]  = bet[nt * 16 + l15];
    }

    const int tstride = gridDim.x;
    const int ntiles  = NE / 64;
    int tile = blockIdx.x;

    // prologue: issue gather loads for first tile
    float4 R[12];
    {
        const int e = tile * 64 + r_st;
        const float* p0 = ndata + (size_t)src[e] * DD + l_st * 16;
        const float* p1 = ndata + (size_t)dst[e] * DD + l_st * 16;
        const float* p2 = edata + (size_t)e * DD + l_st * 16;
#pragma unroll
        for (int jj = 0; jj < 4; ++jj) {
            R[jj]     = ((const float4*)p0)[jj];
            R[4 + jj] = ((const float4*)p1)[jj];
            R[8 + jj] = ((const float4*)p2)[jj];
        }
    }

    while (tile < ntiles) {
        const int e0 = tile * 64;
        const int tn = tile + tstride;

        // prefetch next tile's indices early (latency covered by this tile)
        int sn = 0, dn = 0;
        if (tn < ntiles) {
            const int en = tn * 64 + r_st;
            sn = src[en];
            dn = dst[en];
        }
        // per-output-row indices for the scatter epilogue (broadcast within quad)
        const int4 si4 = *(const int4*)(src + e0 + wave * 16 + quad * 4);
        const int4 di4 = *(const int4*)(dst + e0 + wave * 16 + quad * 4);

        // degree counts (one edge per thread, threads 0..63)
        if (tid < 64) {
            atomicAdd(&cnts[src[e0 + tid]], 1.0f);
            atomicAdd(&cntd[dst[e0 + tid]], 1.0f);
        }

        // consume R -> bf16 LDS (wave-private rows)
#pragma unroll
        for (int seg = 0; seg < 3; ++seg) {
#pragma unroll
            for (int jj = 0; jj < 4; ++jj) {
                const float4 v = R[seg * 4 + jj];
                bf16x4 w = { (bf16)v.x, (bf16)v.y, (bf16)v.z, (bf16)v.w };
                *(bf16x4*)&XH[r_st][seg * 64 + l_st * 16 + jj * 4] = w;
            }
        }
        // A-fragments (ds ops in-order per wave; rows are wave-private)
        const int arow = wave * 16 + l15;
        bf16x8 af[6];
#pragma unroll
        for (int s = 0; s < 6; ++s)
            af[s] = *(const bf16x8*)&XH[arow][s * 32 + quad * 8];

        // issue next tile's gather loads (overlap with GEMM compute below)
        if (tn < ntiles) {
            const int en = tn * 64 + r_st;
            const float* p0 = ndata + (size_t)sn * DD + l_st * 16;
            const float* p1 = ndata + (size_t)dn * DD + l_st * 16;
            const float* p2 = edata + (size_t)en * DD + l_st * 16;
#pragma unroll
            for (int jj = 0; jj < 4; ++jj) {
                R[jj]     = ((const float4*)p0)[jj];
                R[4 + jj] = ((const float4*)p1)[jj];
                R[8 + jj] = ((const float4*)p2)[jj];
            }
        }

        // GEMM1 + GELU -> Hs (overwrites own-wave XH rows after af read)
#pragma unroll
        for (int nt = 0; nt < 8; ++nt) {
            f32x4 acc = {0.f, 0.f, 0.f, 0.f};
#pragma unroll
            for (int s = 0; s < 6; ++s) {
                bf16x8 bfr = *(const bf16x8*)&W1T[nt * 16 + l15][s * 32 + quad * 8];
                acc = __builtin_amdgcn_mfma_f32_16x16x32_bf16(af[s], bfr, acc, 0, 0, 0);
            }
#pragma unroll
            for (int r = 0; r < 4; ++r)
                XH[wave * 16 + quad * 4 + r][nt * 16 + l15] = (bf16)gelu_tanh(acc[r] + b1v[nt]);
        }
        // GEMM2 (W2 from registers)
        bf16x8 af2[4];
#pragma unroll
        for (int s = 0; s < 4; ++s)
            af2[s] = *(const bf16x8*)&XH[wave * 16 + l15][s * 32 + quad * 8];
        float yv[4][4];
        float ps[4] = {0.f, 0.f, 0.f, 0.f}, pq[4] = {0.f, 0.f, 0.f, 0.f};
#pragma unroll
        for (int nt = 0; nt < 4; ++nt) {
            f32x4 acc = {0.f, 0.f, 0.f, 0.f};
#pragma unroll
            for (int s = 0; s < 4; ++s)
                acc = __builtin_amdgcn_mfma_f32_16x16x32_bf16(af2[s], w2f[nt][s], acc, 0, 0, 0);
#pragma unroll
            for (int r = 0; r < 4; ++r) {
                const float y = acc[r] + b2v[nt];
                yv[nt][r] = y;
                ps[r] += y;
                pq[r] += y * y;
            }
        }
        // LayerNorm across the 16 lanes of each quad
#pragma unroll
        for (int m = 1; m < 16; m <<= 1) {
#pragma unroll
            for (int r = 0; r < 4; ++r) {
                ps[r] += __shfl_xor(ps[r], m, 64);
                pq[r] += __shfl_xor(pq[r], m, 64);
            }
        }
        const int sia[4] = { si4.x, si4.y, si4.z, si4.w };
        const int dia[4] = { di4.x, di4.y, di4.z, di4.w };
#pragma unroll
        for (int r = 0; r < 4; ++r) {
            const int row = e0 + wave * 16 + quad * 4 + r;
            const float mu  = ps[r] * (1.0f / 64.0f);
            const float var = pq[r] * (1.0f / 64.0f) - mu * mu;
            const float rs  = rsqrtf(var + 1e-5f);
            const int si = sia[r], di = dia[r];
#pragma unroll
            for (int nt = 0; nt < 4; ++nt) {
                const int col = nt * 16 + l15;
                const float o = (yv[nt][r] - mu) * rs * gv[nt] + bv[nt];
                eout[(size_t)row * DD + col] = o;
                atomicAdd(&eu[(size_t)si * DD + col], o);   // fire-and-forget
                atomicAdd(&ev[(size_t)di * DD + col], o);
            }
        }
        tile = tn;
    }
}

// ---------------------------------------------------------------------------
// Node kernel: 64 nodes per block; dense reads of eu/ev (mean fused) + ndata.
// ---------------------------------------------------------------------------
extern "C" __global__ void __launch_bounds__(256, 2)
node_mlp_kernel(const float* __restrict__ ndata,
                const float* __restrict__ eu, const float* __restrict__ ev,
                const float* __restrict__ cnts, const float* __restrict__ cntd,
                const float* __restrict__ W1, const float* __restrict__ b1,
                const float* __restrict__ W2, const float* __restrict__ b2,
                const float* __restrict__ gam, const float* __restrict__ bet,
                float* __restrict__ nout)
{
    __shared__ __align__(16) bf16 W1T[HH][LDW];
    __shared__ __align__(16) bf16 XH[64][LDW];

    const int tid = threadIdx.x;
    const int wave = tid >> 6;
    const int lane = tid & 63;
    const int l15  = lane & 15;
    const int quad = lane >> 4;
    const int r_st = tid >> 2;
    const int l_st = tid & 3;

    for (int i = tid; i < KK * HH; i += 256) W1T[i & 127][i >> 7] = (bf16)W1[i];
    for (int i = tid; i < HH * DD; i += 256) XH[i & 63][i >> 6] = (bf16)W2[i];
    __syncthreads();
    bf16x8 w2f[4][4];
#pragma unroll
    for (int nt = 0; nt < 4; ++nt)
#pragma unroll
        for (int s = 0; s < 4; ++s)
            w2f[nt][s] = *(const bf16x8*)&XH[nt * 16 + l15][s * 32 + quad * 8];
    __syncthreads();

    float b1v[8], b2v[4], gv[4], bv[4];
#pragma unroll
    for (int nt = 0; nt < 8; ++nt) b1v[nt] = b1[nt * 16 + l15];
#pragma unroll
    for (int nt = 0; nt < 4; ++nt) {
        b2v[nt] = b2[nt * 16 + l15];
        gv[nt]  = gam[nt * 16 + l15];
        bv[nt]  = bet[nt * 16 + l15];
    }

    const int n0 = blockIdx.x * 64;
    const int n  = n0 + r_st;

    // gather x_n = [eu/cnt_s | ev/cnt_d | ndata] -> bf16 LDS (mean fused)
    if (n < NN) {
        const float is  = 1.0f / fmaxf(cnts[n], 1.0f);
        const float idv = 1.0f / fmaxf(cntd[n], 1.0f);
        const float* base0 = eu + (size_t)n * DD + l_st * 16;
        const float* base1 = ev + (size_t)n * DD + l_st * 16;
        const float* base2 = ndata + (size_t)n * DD + l_st * 16;
#pragma unroll
        for (int seg = 0; seg < 3; ++seg) {
            const float* bp = (seg == 0) ? base0 : ((seg == 1) ? base1 : base2);
            const float sc = (seg == 0) ? is : ((seg == 1) ? idv : 1.0f);
#pragma unroll
            for (int jj = 0; jj < 4; ++jj) {
                const float4 v = ((const float4*)bp)[jj];
                bf16x4 w = { (bf16)(v.x * sc), (bf16)(v.y * sc),
                             (bf16)(v.z * sc), (bf16)(v.w * sc) };
                *(bf16x4*)&XH[r_st][seg * 64 + l_st * 16 + jj * 4] = w;
            }
        }
    } else {
        bf16x4 z = { (bf16)0.f, (bf16)0.f, (bf16)0.f, (bf16)0.f };
#pragma unroll
        for (int seg = 0; seg < 3; ++seg)
#pragma unroll
            for (int jj = 0; jj < 4; ++jj)
                *(bf16x4*)&XH[r_st][seg * 64 + l_st * 16 + jj * 4] = z;
    }

    // GEMM1
    const int arow = wave * 16 + l15;
    bf16x8 af[6];
#pragma unroll
    for (int s = 0; s < 6; ++s)
        af[s] = *(const bf16x8*)&XH[arow][s * 32 + quad * 8];
#pragma unroll
    for (int nt = 0; nt < 8; ++nt) {
        f32x4 acc = {0.f, 0.f, 0.f, 0.f};
#pragma unroll
        for (int s = 0; s < 6; ++s) {
            bf16x8 bfr = *(const bf16x8*)&W1T[nt * 16 + l15][s * 32 + quad * 8];
            acc = __builtin_amdgcn_mfma_f32_16x16x32_bf16(af[s], bfr, acc, 0, 0, 0);
        }
#pragma unroll
        for (int r = 0; r < 4; ++r)
            XH[wave * 16 + quad * 4 + r][nt * 16 + l15] = (bf16)gelu_tanh(acc[r] + b1v[nt]);
    }
    // GEMM2
    bf16x8 af2[4];
#pragma unroll
    for (int s = 0; s < 4; ++s)
        af2[s] = *(const bf16x8*)&XH[wave * 16 + l15][s * 32 + quad * 8];
    float yv[4][4];
    float ps[4] = {0.f, 0.f, 0.f, 0.f}, pq[4] = {0.f, 0.f, 0.f, 0.f};
#pragma unroll
    for (int nt = 0; nt < 4; ++nt) {
        f32x4 acc = {0.f, 0.f, 0.f, 0.f};
#pragma unroll
        for (int s = 0; s < 4; ++s)
            acc = __builtin_amdgcn_mfma_f32_16x16x32_bf16(af2[s], w2f[nt][s], acc, 0, 0, 0);
#pragma unroll
        for (int r = 0; r < 4; ++r) {
            const float y = acc[r] + b2v[nt];
            yv[nt][r] = y;
            ps[r] += y;
            pq[r] += y * y;
        }
    }
#pragma unroll
    for (int m = 1; m < 16; m <<= 1) {
#pragma unroll
        for (int r = 0; r < 4; ++r) {
            ps[r] += __shfl_xor(ps[r], m, 64);
            pq[r] += __shfl_xor(pq[r], m, 64);
        }
    }
#pragma unroll
    for (int r = 0; r < 4; ++r) {
        const int row = n0 + wave * 16 + quad * 4 + r;
        if (row < NN) {
            const float mu  = ps[r] * (1.0f / 64.0f);
            const float var = pq[r] * (1.0f / 64.0f) - mu * mu;
            const float rs  = rsqrtf(var + 1e-5f);
#pragma unroll
            for (int nt = 0; nt < 4; ++nt) {
                const int col = nt * 16 + l15;
                nout[(size_t)row * DD + col] = (yv[nt][r] - mu) * rs * gv[nt] + bv[nt];
            }
        }
    }
}

extern "C" void kernel_launch(void* const* d_in, const int* in_sizes, int n_in,
                              void* d_out, int out_size, void* d_ws, size_t ws_size,
                              hipStream_t stream)
{
    const float* ndata = (const float*)d_in[0];
    const float* edata = (const float*)d_in[1];
    const int*   src   = (const int*)d_in[2];
    const int*   dst   = (const int*)d_in[3];
    const float* eW1 = (const float*)d_in[4];
    const float* eb1 = (const float*)d_in[5];
    const float* eW2 = (const float*)d_in[6];
    const float* eb2 = (const float*)d_in[7];
    const float* eg  = (const float*)d_in[8];
    const float* ebt = (const float*)d_in[9];
    const float* nW1 = (const float*)d_in[10];
    const float* nb1 = (const float*)d_in[11];
    const float* nW2 = (const float*)d_in[12];
    const float* nb2 = (const float*)d_in[13];
    const float* ng  = (const float*)d_in[14];
    const float* nbt = (const float*)d_in[15];

    float* out  = (float*)d_out;
    float* nout = out;                       // ndata_new [NN*DD]
    float* eout = out + (size_t)NN * DD;     // edata_new [NE*DD]

    float* eu   = (float*)d_ws;              // [NN*DD]
    float* ev   = eu + (size_t)NN * DD;      // [NN*DD]
    float* cnts = ev + (size_t)NN * DD;      // [NN]
    float* cntd = cnts + NN;                 // [NN]

    const size_t zbytes = ((size_t)2 * NN * DD + 2 * NN) * sizeof(float);
    hipMemsetAsync(d_ws, 0, zbytes, stream);

    hipLaunchKernelGGL(edge_mlp_kernel, dim3(512), dim3(256), 0, stream,
                       ndata, edata, src, dst, eW1, eb1, eW2, eb2, eg, ebt,
                       eout, eu, ev, cnts, cntd);
    hipLaunchKernelGGL(node_mlp_kernel, dim3((NN + 63) / 64), dim3(256), 0, stream,
                       ndata, eu, ev, cnts, cntd, nW1, nb1, nW2, nb2, ng, nbt,
                       nout);
}